// Round 1
// baseline (565.577 us; speedup 1.0000x reference)
//
#include <hip/hip_runtime.h>

#define B_ 16
#define N_ 2048
#define M_ 2048
#define ROWS 64    // rows per block (band)
#define WROWS 16   // rows per wave (4 waves/block)

__device__ __forceinline__ float wave_sum(float v) {
#pragma unroll
    for (int off = 32; off >= 1; off >>= 1) v += __shfl_xor(v, off);
    return v;
}

// Pass 1: row_gt/row_cnt (row sums of pred*gt, gt) + col_gt/col_cnt (col sums)
extern "C" __global__ __launch_bounds__(256) void k_pass1(
    const float* __restrict__ pred, const float* __restrict__ gt,
    const int* __restrict__ src_ns, const int* __restrict__ tgt_ns,
    float* __restrict__ row_gt, float* __restrict__ row_cnt,
    float* __restrict__ col_gt, float* __restrict__ col_cnt)
{
    const int b = blockIdx.y;
    const int src = src_ns[b];
    const int band = blockIdx.x;
    if (band * ROWS >= src) return;   // whole band masked out
    const int tgt = tgt_ns[b];
    const int wave = threadIdx.x >> 6, lane = threadIdx.x & 63;
    const int base = b * (N_ * M_);

    float4 acg[8], accn[8];
#pragma unroll
    for (int j = 0; j < 8; ++j) { acg[j] = make_float4(0,0,0,0); accn[j] = make_float4(0,0,0,0); }

    const int row0 = band * ROWS + wave * WROWS;
    for (int r = 0; r < WROWS; ++r) {
        const int n = row0 + r;
        if (n >= src) break;          // rows ascending; wave-uniform
        const float4* prow = (const float4*)(pred + base + n * M_);
        const float4* grow = (const float4*)(gt + base + n * M_);
        float rg = 0.f, rc = 0.f;
#pragma unroll
        for (int j = 0; j < 8; ++j) {
            const int m4 = j * 64 + lane;
            const float4 p4 = prow[m4];
            const float4 g4 = grow[m4];
            const int mb = m4 * 4;
#define P1C(K, MB) do { \
    const bool ok = (mb + K) < tgt; \
    float p = fminf(fmaxf(p4.MB, 0.f), 1.f); p = ok ? p : 0.f; \
    const float g = ok ? g4.MB : 0.f; \
    const float gp = p * g; \
    rg += gp; rc += g; \
    acg[j].MB += gp; accn[j].MB += g; \
} while (0)
            P1C(0, x); P1C(1, y); P1C(2, z); P1C(3, w);
#undef P1C
        }
        rg = wave_sum(rg); rc = wave_sum(rc);
        if (lane == 0) { row_gt[b * N_ + n] = rg; row_cnt[b * N_ + n] = rc; }
    }

    // combine column partials across the 4 waves in LDS (sequential rounds, no atomics)
    __shared__ float4 s_cg[M_ / 4];
    __shared__ float4 s_cc[M_ / 4];
    for (int i = threadIdx.x; i < M_ / 4; i += 256) {
        s_cg[i] = make_float4(0,0,0,0);
        s_cc[i] = make_float4(0,0,0,0);
    }
    __syncthreads();
    for (int w = 0; w < 4; ++w) {
        if (wave == w) {
#pragma unroll
            for (int j = 0; j < 8; ++j) {
                const int i = j * 64 + lane;
                float4 v = s_cg[i];
                v.x += acg[j].x; v.y += acg[j].y; v.z += acg[j].z; v.w += acg[j].w;
                s_cg[i] = v;
                float4 u = s_cc[i];
                u.x += accn[j].x; u.y += accn[j].y; u.z += accn[j].z; u.w += accn[j].w;
                s_cc[i] = u;
            }
        }
        __syncthreads();
    }
    const float* fcg = (const float*)s_cg;
    const float* fcc = (const float*)s_cc;
    for (int i = threadIdx.x; i < M_; i += 256) {
        atomicAdd(&col_gt[b * M_ + i], fcg[i]);
        atomicAdd(&col_cnt[b * M_ + i], fcc[i]);
    }
}

// Pass 2: src_neg/src_pos (row reductions) + tgt_neg (col reduction)
extern "C" __global__ __launch_bounds__(256) void k_pass2(
    const float* __restrict__ pred, const float* __restrict__ gt,
    const int* __restrict__ src_ns, const int* __restrict__ tgt_ns,
    const float* __restrict__ beta_p,
    const float* __restrict__ row_gt, const float* __restrict__ row_cnt,
    const float* __restrict__ col_gt, const float* __restrict__ col_cnt,
    float* __restrict__ src_neg, float* __restrict__ src_pos,
    float* __restrict__ tgt_neg)
{
    const int b = blockIdx.y;
    const int src = src_ns[b];
    const int band = blockIdx.x;
    if (band * ROWS >= src) return;
    const int tgt = tgt_ns[b];
    const float beta = beta_p[0];
    const int wave = threadIdx.x >> 6, lane = threadIdx.x & 63;
    const int base = b * (N_ * M_);

    float4 cg[8], cc[8], tn[8];
    const float4* cg4 = (const float4*)(col_gt + b * M_);
    const float4* cc4 = (const float4*)(col_cnt + b * M_);
#pragma unroll
    for (int j = 0; j < 8; ++j) {
        cg[j] = cg4[j * 64 + lane];
        cc[j] = cc4[j * 64 + lane];
        tn[j] = make_float4(0,0,0,0);
    }

    const int row0 = band * ROWS + wave * WROWS;
    for (int r = 0; r < WROWS; ++r) {
        const int n = row0 + r;
        if (n >= src) break;
        const float rg = row_gt[b * N_ + n];
        const float rc = row_cnt[b * N_ + n];
        const float rth = rg - beta;
        const float4* prow = (const float4*)(pred + base + n * M_);
        const float4* grow = (const float4*)(gt + base + n * M_);
        float sneg = 0.f, spos = 0.f;
#pragma unroll
        for (int j = 0; j < 8; ++j) {
            const int m4 = j * 64 + lane;
            const float4 p4 = prow[m4];
            const float4 g4 = grow[m4];
            const int mb = m4 * 4;
#define P2C(K, MB) do { \
    const bool ok = (mb + K) < tgt; \
    float p = fminf(fmaxf(p4.MB, 0.f), 1.f); p = ok ? p : 0.f; \
    const float g = ok ? g4.MB : 0.f; \
    const float gp = p * g; \
    const float as = (ok && (p >= rth)) ? rc : 0.f; \
    const float ds = (as - g) * p; \
    sneg += ds * ds; spos += gp * gp; \
    const float at = (ok && (p >= cg[j].MB - beta)) ? cc[j].MB : 0.f; \
    const float dt = (at - g) * p; \
    tn[j].MB += dt * dt; \
} while (0)
            P2C(0, x); P2C(1, y); P2C(2, z); P2C(3, w);
#undef P2C
        }
        sneg = wave_sum(sneg); spos = wave_sum(spos);
        if (lane == 0) { src_neg[b * N_ + n] = sneg; src_pos[b * N_ + n] = spos; }
    }

    __shared__ float4 s_tn[M_ / 4];
    for (int i = threadIdx.x; i < M_ / 4; i += 256) s_tn[i] = make_float4(0,0,0,0);
    __syncthreads();
    for (int w = 0; w < 4; ++w) {
        if (wave == w) {
#pragma unroll
            for (int j = 0; j < 8; ++j) {
                const int i = j * 64 + lane;
                float4 v = s_tn[i];
                v.x += tn[j].x; v.y += tn[j].y; v.z += tn[j].z; v.w += tn[j].w;
                s_tn[i] = v;
            }
        }
        __syncthreads();
    }
    const float* ftn = (const float*)s_tn;
    for (int i = threadIdx.x; i < M_; i += 256)
        atomicAdd(&tgt_neg[b * M_ + i], ftn[i]);
}

// Final: corr[b] = dot(tgt_neg, col_cnt), then loss reduction -> single scalar
extern "C" __global__ __launch_bounds__(256) void k_final(
    const float* __restrict__ src_neg, const float* __restrict__ src_pos,
    const float* __restrict__ tgt_neg, const float* __restrict__ col_cnt,
    const int* __restrict__ src_ns, float* __restrict__ out)
{
    const int b = blockIdx.x;
    const int wave = threadIdx.x >> 6, lane = threadIdx.x & 63;
    __shared__ float sredc[4];
    __shared__ float sredl[4];

    float c = 0.f;
    for (int i = threadIdx.x; i < M_; i += 256)
        c += tgt_neg[b * M_ + i] * col_cnt[b * M_ + i];
    c = wave_sum(c);
    if (lane == 0) sredc[wave] = c;
    __syncthreads();
    const float corr = sredc[0] + sredc[1] + sredc[2] + sredc[3];

    const int src = src_ns[b];
    float ls = 0.f;
    for (int n = threadIdx.x; n < src; n += 256) {
        const float sp = src_pos[b * N_ + n];
        const float sn = src_neg[b * N_ + n];
        ls += logf(sp) - logf(1.f + sn + corr);
    }
    ls = wave_sum(ls);
    if (lane == 0) sredl[wave] = ls;
    __syncthreads();
    if (threadIdx.x == 0) {
        const float total = sredl[0] + sredl[1] + sredl[2] + sredl[3];
        float nsum = 0.f;
        for (int i = 0; i < B_; ++i) nsum += (float)src_ns[i];
        atomicAdd(out, -0.5f * total / nsum);
    }
}

extern "C" void kernel_launch(void* const* d_in, const int* in_sizes, int n_in,
                              void* d_out, int out_size, void* d_ws, size_t ws_size,
                              hipStream_t stream)
{
    const float* pred   = (const float*)d_in[0];
    const float* gtp    = (const float*)d_in[1];
    const int*   src_ns = (const int*)d_in[2];
    const int*   tgt_ns = (const int*)d_in[3];
    const float* beta   = (const float*)d_in[4];
    float* out = (float*)d_out;
    float* ws  = (float*)d_ws;

    float* row_gt  = ws;
    float* row_cnt = row_gt  + B_ * N_;
    float* col_gt  = row_cnt + B_ * N_;
    float* col_cnt = col_gt  + B_ * M_;
    float* src_neg = col_cnt + B_ * M_;
    float* src_pos = src_neg + B_ * N_;
    float* tgt_neg = src_pos + B_ * N_;

    const size_t zero_bytes = (size_t)(4 * B_ * N_ + 3 * B_ * M_) * sizeof(float);
    hipMemsetAsync(d_ws, 0, zero_bytes, stream);
    hipMemsetAsync(d_out, 0, sizeof(float), stream);

    dim3 grid(N_ / ROWS, B_);
    k_pass1<<<grid, 256, 0, stream>>>(pred, gtp, src_ns, tgt_ns,
                                      row_gt, row_cnt, col_gt, col_cnt);
    k_pass2<<<grid, 256, 0, stream>>>(pred, gtp, src_ns, tgt_ns, beta,
                                      row_gt, row_cnt, col_gt, col_cnt,
                                      src_neg, src_pos, tgt_neg);
    k_final<<<B_, 256, 0, stream>>>(src_neg, src_pos, tgt_neg, col_cnt, src_ns, out);
}